// Round 10
// baseline (217.618 us; speedup 1.0000x reference)
//
#include <hip/hip_runtime.h>
#include <hip/hip_bf16.h>
#include <math.h>

// BlockSparseAttention: x[1,4096,1024] fp32; w_qkv[3072,1024], b_qkv[3072],
// w_out[1024,1024], b_out[1024] fp32. out[4096,1024] fp32.
// blocks of 128; global blocks {0,24}; qb attends {0,qb,24} (or all if qb global).

#define SEQ 4096
#define DIM 1024
#define NHEADS 16
#define HDIM 64
#define BS 128
#define ESTRIDE 136   // gemm epilogue staging pad

using short8 = __attribute__((ext_vector_type(8))) short;   // 8 x bf16 bits
using floatx4 = __attribute__((ext_vector_type(4))) float;

__device__ __forceinline__ float bf2f(short s) {
  unsigned u = ((unsigned)(unsigned short)s) << 16;
  return __uint_as_float(u);
}

__device__ __forceinline__ unsigned pack_bf16(float a, float b) {
  __hip_bfloat16 ba = __float2bfloat16(a);
  __hip_bfloat16 bb = __float2bfloat16(b);
  return ((unsigned)*(unsigned short*)&bb << 16) | (unsigned)*(unsigned short*)&ba;
}

__device__ __forceinline__ void gld_lds16(const __hip_bfloat16* g, __hip_bfloat16* l) {
  // 16B per lane, dest = wave-uniform base + lane*16 [guide §5, m97/m104]
  __builtin_amdgcn_global_load_lds(
      (const __attribute__((address_space(1))) unsigned int*)g,
      (__attribute__((address_space(3))) unsigned int*)l, 16, 0, 0);
}

// ---------------------------------------------------------------------------
// merged fp32 -> bf16 downcast for x (4096 blks), w_qkv (3072), w_out (1024)
// ---------------------------------------------------------------------------
__global__ __launch_bounds__(256) void downcast3(
    const float* __restrict__ x, const float* __restrict__ wq,
    const float* __restrict__ wo, __hip_bfloat16* __restrict__ xd,
    __hip_bfloat16* __restrict__ wqd, __hip_bfloat16* __restrict__ wod) {
  int id = blockIdx.x;
  const float* src;
  __hip_bfloat16* dst;
  int base;
  if (id < 4096) { src = x; dst = xd; base = id; }
  else if (id < 7168) { src = wq; dst = wqd; base = id - 4096; }
  else { src = wo; dst = wod; base = id - 7168; }
  int i = (base * 256 + threadIdx.x) * 4;
  float4 v = *(const float4*)(src + i);
  __hip_bfloat16 b0 = __float2bfloat16(v.x);
  __hip_bfloat16 b1 = __float2bfloat16(v.y);
  __hip_bfloat16 b2 = __float2bfloat16(v.z);
  __hip_bfloat16 b3 = __float2bfloat16(v.w);
  ushort4 packed = {*(unsigned short*)&b0, *(unsigned short*)&b1,
                    *(unsigned short*)&b2, *(unsigned short*)&b3};
  *(ushort4*)(((unsigned short*)dst) + i) = packed;
}

// ---------------------------------------------------------------------------
// QKV GEMM (unchanged): m97 K-loop + LDS-staged coalesced epilogue with
// operand swap for Q/K (transposed D) vs V (direct D -> Vt).
// ---------------------------------------------------------------------------
__global__ __launch_bounds__(256) void gemm_qkv(const __hip_bfloat16* __restrict__ Amat,
                                                const __hip_bfloat16* __restrict__ Wmat,
                                                const float* __restrict__ Bias,
                                                __hip_bfloat16* __restrict__ qkv) {
  __shared__ __align__(16) char pool[128 * ESTRIDE * 2];  // 34816 B
  __hip_bfloat16* Asmem = (__hip_bfloat16*)pool;
  __hip_bfloat16* Bsmem = (__hip_bfloat16*)(pool + 8192);
  __hip_bfloat16* Ep = (__hip_bfloat16*)pool;

  const int Kd = DIM;
  const int t = threadIdx.x;
  const int w = t >> 6;
  const int lane = t & 63;
  const int fr = lane & 15;
  const int quad = lane >> 4;
  const int wm = w >> 1, wn = w & 1;

  int id = blockIdx.x;
  int xcd = id & 7, j = id >> 3;
  int m_idx = xcd + (j & 3) * 8;
  int n_idx = j >> 2;
  const int m0 = m_idx * 128;
  const int n0 = n_idx * 128;
  const int s = n0 >> 10;
  const int cc0 = n0 & 1023;
  const bool vmode = (s == 2);

  const __hip_bfloat16* APtr = vmode ? Amat + (size_t)m0 * Kd : Wmat + (size_t)n0 * Kd;
  const __hip_bfloat16* BPtr = vmode ? Wmat + (size_t)n0 * Kd : Amat + (size_t)m0 * Kd;

  floatx4 acc[4][4];
#pragma unroll
  for (int i = 0; i < 4; ++i)
#pragma unroll
    for (int jj = 0; jj < 4; ++jj) acc[i][jj] = (floatx4){0.f, 0.f, 0.f, 0.f};

  for (int kk = 0; kk < Kd / 32; ++kk) {
#pragma unroll
    for (int jj = 0; jj < 2; ++jj) {
      int c = jj * 256 + t;
      int ldso = (jj * 256 + w * 64) * 8;
      gld_lds16(APtr + (size_t)(c >> 2) * Kd + kk * 32 + (c & 3) * 8, &Asmem[ldso]);
      gld_lds16(BPtr + (size_t)(c >> 2) * Kd + kk * 32 + (c & 3) * 8, &Bsmem[ldso]);
    }
    __syncthreads();
    short8 af[4], bf_[4];
#pragma unroll
    for (int mt = 0; mt < 4; ++mt)
      af[mt] = *(const short8*)&Asmem[(wm * 64 + mt * 16 + fr) * 32 + quad * 8];
#pragma unroll
    for (int nt = 0; nt < 4; ++nt)
      bf_[nt] = *(const short8*)&Bsmem[(wn * 64 + nt * 16 + fr) * 32 + quad * 8];
#pragma unroll
    for (int mt = 0; mt < 4; ++mt)
#pragma unroll
      for (int nt = 0; nt < 4; ++nt)
        acc[mt][nt] = __builtin_amdgcn_mfma_f32_16x16x32_bf16(af[mt], bf_[nt],
                                                              acc[mt][nt], 0, 0, 0);
    __syncthreads();
  }

#pragma unroll
  for (int nt = 0; nt < 4; ++nt) {
    int dcol = wn * 64 + nt * 16 + fr;
#pragma unroll
    for (int mt = 0; mt < 4; ++mt) {
      int drow0 = wm * 64 + mt * 16 + quad * 4;
      ushort4 pk;
      unsigned short* pks = (unsigned short*)&pk;
#pragma unroll
      for (int i = 0; i < 4; ++i) {
        __hip_bfloat16 bb = __float2bfloat16(acc[mt][nt][i]);
        pks[i] = *(unsigned short*)&bb;
      }
      *(ushort4*)&Ep[dcol * ESTRIDE + drow0] = pk;
    }
  }
  __syncthreads();

  if (!vmode) {
    __hip_bfloat16* dst = qkv + (size_t)s * SEQ * DIM;
#pragma unroll
    for (int rr = 0; rr < 8; ++rr) {
      int m = rr * 16 + (t >> 4);
      int ch = (t & 15) * 8;
      short8 v8 = *(const short8*)&Ep[m * ESTRIDE + ch];
      float4 b0 = *(const float4*)&Bias[n0 + ch];
      float4 b1 = *(const float4*)&Bias[n0 + ch + 4];
      float bb[8] = {b0.x, b0.y, b0.z, b0.w, b1.x, b1.y, b1.z, b1.w};
      short8 o8;
#pragma unroll
      for (int k = 0; k < 8; ++k) {
        __hip_bfloat16 ob = __float2bfloat16(bf2f(v8[k]) + bb[k]);
        o8[k] = *(short*)&ob;
      }
      *(short8*)&dst[(size_t)(m0 + m) * DIM + cc0 + ch] = o8;
    }
  } else {
    __hip_bfloat16* vt = qkv + 2ull * SEQ * DIM;
#pragma unroll
    for (int rr = 0; rr < 8; ++rr) {
      int nrow = rr * 16 + (t >> 4);
      int ch = (t & 15) * 8;
      float bv = Bias[n0 + nrow];
      short8 v8 = *(const short8*)&Ep[nrow * ESTRIDE + ch];
      short8 o8;
#pragma unroll
      for (int k = 0; k < 8; ++k) {
        __hip_bfloat16 ob = __float2bfloat16(bf2f(v8[k]) + bv);
        o8[k] = *(short*)&ob;
      }
      *(short8*)&vt[(size_t)(cc0 + nrow) * SEQ + m0 + ch] = o8;
    }
  }
}

// ---------------------------------------------------------------------------
// out-proj GEMM: 128x64 tiles -> 512 wgs (2/CU) (unchanged).
// ---------------------------------------------------------------------------
__global__ __launch_bounds__(256) void gemm_out(const __hip_bfloat16* __restrict__ Amat,
                                                const __hip_bfloat16* __restrict__ Wmat,
                                                const float* __restrict__ Bias,
                                                float* __restrict__ out) {
  __shared__ __align__(16) __hip_bfloat16 Asmem[128 * 32];
  __shared__ __align__(16) __hip_bfloat16 Bsmem[64 * 32];
  const int Kd = DIM;
  const int t = threadIdx.x;
  const int w = t >> 6;
  const int lane = t & 63;
  const int fr = lane & 15;
  const int quad = lane >> 4;
  const int wm = w >> 1, wn = w & 1;
  int id = blockIdx.x;
  int xcd = id & 7, j = id >> 3;       // j in [0,64)
  int m_idx = xcd + (j & 3) * 8;       // 0..31
  int n_idx = j >> 2;                  // 0..15
  const int m0 = m_idx * 128;
  const int n0 = n_idx * 64;
  const __hip_bfloat16* Ablk = Amat + (size_t)m0 * Kd;
  const __hip_bfloat16* Bblk = Wmat + (size_t)n0 * Kd;
  floatx4 acc[4][2];
#pragma unroll
  for (int i = 0; i < 4; ++i)
#pragma unroll
    for (int jj = 0; jj < 2; ++jj) acc[i][jj] = (floatx4){0.f, 0.f, 0.f, 0.f};
  for (int kk = 0; kk < Kd / 32; ++kk) {
#pragma unroll
    for (int jj = 0; jj < 2; ++jj) {
      int c = jj * 256 + t;
      int ldso = (jj * 256 + w * 64) * 8;
      gld_lds16(Ablk + (size_t)(c >> 2) * Kd + kk * 32 + (c & 3) * 8, &Asmem[ldso]);
    }
    gld_lds16(Bblk + (size_t)(t >> 2) * Kd + kk * 32 + (t & 3) * 8, &Bsmem[t * 8]);
    __syncthreads();
    short8 af[4], bf_[2];
#pragma unroll
    for (int mt = 0; mt < 4; ++mt)
      af[mt] = *(const short8*)&Asmem[(wm * 64 + mt * 16 + fr) * 32 + quad * 8];
#pragma unroll
    for (int nt = 0; nt < 2; ++nt)
      bf_[nt] = *(const short8*)&Bsmem[(wn * 32 + nt * 16 + fr) * 32 + quad * 8];
#pragma unroll
    for (int mt = 0; mt < 4; ++mt)
#pragma unroll
      for (int nt = 0; nt < 2; ++nt)
        acc[mt][nt] = __builtin_amdgcn_mfma_f32_16x16x32_bf16(af[mt], bf_[nt],
                                                              acc[mt][nt], 0, 0, 0);
    __syncthreads();
  }
#pragma unroll
  for (int nt = 0; nt < 2; ++nt) {
    int n = n0 + wn * 32 + nt * 16 + fr;
    float bv = Bias[n];
#pragma unroll
    for (int mt = 0; mt < 4; ++mt) {
      int m = m0 + wm * 64 + mt * 16 + quad * 4;
#pragma unroll
      for (int i = 0; i < 4; ++i)
        out[(size_t)(m + i) * DIM + n] = acc[mt][nt][i] + bv;
    }
  }
}

// ---------------------------------------------------------------------------
// MFMA flash attention, S^T formulation — occupancy round:
//  * __launch_bounds__(256, 8): force VGPR<=64 -> 8 waves/SIMD class [m69]
//  * single 16KB KV buffer, K-then-V sequential staging (4 barriers/iter)
//    -> LDS no longer binding; 8 wgs/CU -> 1472-wg grid fits ONE residency
//    round (was 2 rounds at 4 wgs/CU).
//  * PV reordered ks2-outer so only one repacked P-frag (4 VGPRs) is live.
// Math identical to round 9 (verified repack: select AFTER shfl).
// ---------------------------------------------------------------------------
__global__ __launch_bounds__(256, 8) void attn_mfma(
    const __hip_bfloat16* __restrict__ qkv,
    __hip_bfloat16* __restrict__ aout,
    float* __restrict__ po, float* __restrict__ pm, float* __restrict__ pl) {
  __shared__ __align__(16) __hip_bfloat16 KVbuf[16 * 512];   // 16KB, 16 frags
  const int h = blockIdx.y;
  const int wgid = blockIdx.x;
  const int t = threadIdx.x;
  const int wv = t >> 6;
  const int lane = t & 63;
  const int fr = lane & 15;
  const int quad = lane >> 4;

  int qb, q0, niter, slice = 0, pid = 0;
  bool direct;
  if (wgid < 60) {
    int nb = wgid >> 1;                 // 0..29
    qb = (nb < 23) ? nb + 1 : nb + 2;   // 1..23, 25..31
    q0 = qb * BS + (wgid & 1) * 64;
    niter = 3;
    direct = true;
  } else {
    int gi = wgid - 60;                 // 0..31
    slice = gi & 7;
    int chunk = gi >> 3;                // 0..3
    qb = (chunk >> 1) * 24;             // 0 or 24
    q0 = qb * BS + (chunk & 1) * 64;
    niter = 4;
    direct = false;
    pid = (h * 4 + chunk) * 8 + slice;
  }

  const __hip_bfloat16* Q = qkv;
  const __hip_bfloat16* K = qkv + (size_t)SEQ * DIM;
  const __hip_bfloat16* Vt = qkv + 2ull * SEQ * DIM;  // [DIM][SEQ]

  // Q B-frags: lane holds Q[row=fr][dim=quad*8+j] (+32 for chunk 1)
  short8 qa0, qa1;
  {
    const __hip_bfloat16* qp =
        Q + (size_t)(q0 + wv * 16 + fr) * DIM + h * HDIM + quad * 8;
    qa0 = *(const short8*)(qp);
    qa1 = *(const short8*)(qp + 32);
  }

  float mrow = -INFINITY, lsum = 0.f;
  floatx4 o[4];
#pragma unroll
  for (int i = 0; i < 4; ++i) o[i] = (floatx4){0.f, 0.f, 0.f, 0.f};

  for (int bi = 0; bi < niter; ++bi) {
    int kb = direct ? (bi == 0 ? 0 : (bi == 1 ? qb : 24)) : slice * 4 + bi;

    // ---- stage K tile (frag-major) into shared KVbuf ----
    const __hip_bfloat16* Kg = K + (size_t)(kb * BS) * DIM + h * HDIM;
    __syncthreads();  // prior PV done reading KVbuf
#pragma unroll
    for (int rr = 0; rr < 4; ++rr) {
      int f = rr * 4 + wv;              // wave-uniform frag id
      int nt = f >> 1, ks = f & 1;
      gld_lds16(Kg + (size_t)(nt * 16 + fr) * DIM + ks * 32 + quad * 8,
                &KVbuf[f * 512]);
    }
    __syncthreads();  // K visible (vmcnt(0) drained at barrier)

    // ---- St = K.Q^T: lane holds St[key=nt*16+quad*4+i][row=fr] ----
    floatx4 s[8];
#pragma unroll
    for (int nt = 0; nt < 8; ++nt) {
      short8 kf0 = *(const short8*)&KVbuf[(nt * 2 + 0) * 512 + lane * 8];
      short8 kf1 = *(const short8*)&KVbuf[(nt * 2 + 1) * 512 + lane * 8];
      floatx4 acc = {0.f, 0.f, 0.f, 0.f};
      acc = __builtin_amdgcn_mfma_f32_16x16x32_bf16(kf0, qa0, acc, 0, 0, 0);
      acc = __builtin_amdgcn_mfma_f32_16x16x32_bf16(kf1, qa1, acc, 0, 0, 0);
      s[nt] = acc;
    }
#pragma unroll
    for (int nt = 0; nt < 8; ++nt)
#pragma unroll
      for (int i = 0; i < 4; ++i) s[nt][i] *= 0.125f;

    // ---- lane-local online softmax (row = fr) ----
    float rmax = -INFINITY;
#pragma unroll
    for (int nt = 0; nt < 8; ++nt)
#pragma unroll
      for (int i = 0; i < 4; ++i) rmax = fmaxf(rmax, s[nt][i]);
    rmax = fmaxf(rmax, __shfl_xor(rmax, 16, 64));
    rmax = fmaxf(rmax, __shfl_xor(rmax, 32, 64));
    float newm = fmaxf(mrow, rmax);
    float alpha = __expf(mrow - newm);   // first iter: exp(-inf)=0
    float psum = 0.f;
    unsigned pki[8][2];
#pragma unroll
    for (int nt = 0; nt < 8; ++nt) {
      float p0 = __expf(s[nt][0] - newm);
      float p1 = __expf(s[nt][1] - newm);
      float p2 = __expf(s[nt][2] - newm);
      float p3 = __expf(s[nt][3] - newm);
      psum += (p0 + p1) + (p2 + p3);
      pki[nt][0] = pack_bf16(p0, p1);
      pki[nt][1] = pack_bf16(p2, p3);
    }
    psum += __shfl_xor(psum, 16, 64);
    psum += __shfl_xor(psum, 32, 64);
    lsum = lsum * alpha + psum;
    mrow = newm;
#pragma unroll
    for (int nt2 = 0; nt2 < 4; ++nt2)
#pragma unroll
      for (int i = 0; i < 4; ++i) o[nt2][i] *= alpha;

    // ---- stage V tile (frag-major) into the same KVbuf ----
    const __hip_bfloat16* Vg = Vt + (size_t)(h * HDIM) * SEQ + kb * BS;
    __syncthreads();  // all waves done reading K
#pragma unroll
    for (int rr = 0; rr < 4; ++rr) {
      int f = rr * 4 + wv;
      int nt2 = f >> 2, ks2 = f & 3;
      gld_lds16(Vg + (size_t)(nt2 * 16 + fr) * SEQ + ks2 * 32 + quad * 8,
                &KVbuf[f * 512]);
    }
    __syncthreads();  // V visible

    // ---- repack + PV, ks2-outer (one pw live at a time) ----
#pragma unroll
    for (int ks2 = 0; ks2 < 4; ++ks2) {
      union { int w4[4]; short8 s8; } pw;
#pragma unroll
      for (int p = 0; p < 4; ++p) {
        int srcl = fr + ((((quad & 1) << 1) + (p >> 1)) << 4);
        int lo = __shfl((int)pki[2 * ks2][p & 1], srcl, 64);
        int hi = __shfl((int)pki[2 * ks2 + 1][p & 1], srcl, 64);
        pw.w4[p] = (quad & 2) ? hi : lo;
      }
#pragma unroll
      for (int nt2 = 0; nt2 < 4; ++nt2) {
        short8 vb = *(const short8*)&KVbuf[(nt2 * 4 + ks2) * 512 + lane * 8];
        o[nt2] = __builtin_amdgcn_mfma_f32_16x16x32_bf16(vb, pw.s8, o[nt2], 0, 0, 0);
      }
    }
  }

  // O^T C-layout: lane holds O[row=fr][d = nt2*16 + quad*4 + i] -> contiguous
  if (direct) {
    float inv = 1.f / lsum;
    __hip_bfloat16* orow = aout + (size_t)(q0 + wv * 16 + fr) * DIM + h * HDIM + quad * 4;
#pragma unroll
    for (int nt2 = 0; nt2 < 4; ++nt2) {
      ushort4 pk;
      unsigned short* pks = (unsigned short*)&pk;
#pragma unroll
      for (int i = 0; i < 4; ++i) {
        __hip_bfloat16 ob = __float2bfloat16(o[nt2][i] * inv);
        pks[i] = *(unsigned short*)&ob;
      }
      *(ushort4*)(orow + nt2 * 16) = pk;
    }
  } else {
    float* pob = po + (size_t)pid * 4096 + (wv * 16 + fr) * 64 + quad * 4;
#pragma unroll
    for (int nt2 = 0; nt2 < 4; ++nt2) {
      float4 v = {o[nt2][0], o[nt2][1], o[nt2][2], o[nt2][3]};
      *(float4*)(pob + nt2 * 16) = v;
    }
    if (quad == 0) {
      pm[pid * 64 + wv * 16 + fr] = mrow;
      pl[pid * 64 + wv * 16 + fr] = lsum;
    }
  }
}

// ---------------------------------------------------------------------------
// Combine 8 KV-slice partials for the global q-blocks (unchanged).
// ---------------------------------------------------------------------------
__global__ __launch_bounds__(256) void combine(const float* __restrict__ po,
                                               const float* __restrict__ pm,
                                               const float* __restrict__ pl,
                                               __hip_bfloat16* __restrict__ aout) {
  int b = blockIdx.x;  // h*4 + chunk
  int h = b >> 2, chunk = b & 3;
  int t = threadIdx.x;
  int row = t >> 2;
  int d0 = (t & 3) * 16;

  float m8[8];
  float newm = -INFINITY;
#pragma unroll
  for (int s = 0; s < 8; ++s) {
    m8[s] = pm[(b * 8 + s) * 64 + row];
    newm = fmaxf(newm, m8[s]);
  }
  float wgt[8], lsum = 0.f;
#pragma unroll
  for (int s = 0; s < 8; ++s) {
    wgt[s] = __expf(m8[s] - newm);
    lsum += pl[(b * 8 + s) * 64 + row] * wgt[s];
  }
  float acc[16];
#pragma unroll
  for (int jj = 0; jj < 16; ++jj) acc[jj] = 0.f;
#pragma unroll
  for (int s = 0; s < 8; ++s) {
    const float* src = po + ((size_t)(b * 8 + s) * 4096) + row * 64 + d0;
#pragma unroll
    for (int j4 = 0; j4 < 4; ++j4) {
      float4 v = *(const float4*)(src + j4 * 4);
      acc[j4 * 4 + 0] += wgt[s] * v.x;
      acc[j4 * 4 + 1] += wgt[s] * v.y;
      acc[j4 * 4 + 2] += wgt[s] * v.z;
      acc[j4 * 4 + 3] += wgt[s] * v.w;
    }
  }
  float inv = 1.f / lsum;
  int qrow = (chunk >> 1) * 3072 + (chunk & 1) * 64 + row;
#pragma unroll
  for (int jj = 0; jj < 16; ++jj)
    aout[(size_t)qrow * DIM + h * HDIM + d0 + jj] = __float2bfloat16(acc[jj] * inv);
}

// ---------------------------------------------------------------------------
extern "C" void kernel_launch(void* const* d_in, const int* in_sizes, int n_in,
                              void* d_out, int out_size, void* d_ws, size_t ws_size,
                              hipStream_t stream) {
  const float* x = (const float*)d_in[0];
  const float* w_qkv = (const float*)d_in[1];
  const float* b_qkv = (const float*)d_in[2];
  const float* w_out = (const float*)d_in[3];
  const float* b_out = (const float*)d_in[4];
  float* out = (float*)d_out;

  // ws layout (bytes):
  //   [0,   24M) bf16 qkv: Q[SEQ][DIM], K[SEQ][DIM], Vt[DIM][SEQ]
  //   [24M, 32M) bf16 x_bf   -- dead after gemm_qkv; reused as po (8MB fp32)
  //   [32M, 38M) bf16 wqkv_bf -- dead after gemm_qkv; first 256KB reused as pm/pl
  //   [38M, 40M) bf16 wout_bf
  //   [40M, 48M) bf16 attn_ws [SEQ][DIM]
  char* wsb = (char*)d_ws;
  __hip_bfloat16* qkv_ws = (__hip_bfloat16*)(wsb);
  __hip_bfloat16* x_bf = (__hip_bfloat16*)(wsb + 24ull * 1024 * 1024);
  __hip_bfloat16* wqkv_bf = (__hip_bfloat16*)(wsb + 32ull * 1024 * 1024);
  __hip_bfloat16* wout_bf = (__hip_bfloat16*)(wsb + 38ull * 1024 * 1024);
  __hip_bfloat16* attn_ws = (__hip_bfloat16*)(wsb + 40ull * 1024 * 1024);
  float* po = (float*)(wsb + 24ull * 1024 * 1024);           // 512*64*64*4 = 8MB
  float* pm = (float*)(wsb + 32ull * 1024 * 1024);           // 128KB
  float* pl = (float*)(wsb + 32ull * 1024 * 1024 + 131072);  // 128KB

  dim3 blk(256);
  downcast3<<<dim3(8192), blk, 0, stream>>>(x, w_qkv, w_out, x_bf, wqkv_bf, wout_bf);
  gemm_qkv<<<dim3(768), blk, 0, stream>>>(x_bf, wqkv_bf, b_qkv, qkv_ws);
  attn_mfma<<<dim3(92, NHEADS), blk, 0, stream>>>(qkv_ws, attn_ws, po, pm, pl);
  combine<<<dim3(64), blk, 0, stream>>>(po, pm, pl, attn_ws);
  gemm_out<<<dim3(512), blk, 0, stream>>>(attn_ws, wout_bf, b_out, out);
}

// Round 11
// 178.490 us; speedup vs baseline: 1.2192x; 1.2192x over previous
//
#include <hip/hip_runtime.h>
#include <hip/hip_bf16.h>
#include <math.h>

// BlockSparseAttention: x[1,4096,1024] fp32; w_qkv[3072,1024], b_qkv[3072],
// w_out[1024,1024], b_out[1024] fp32. out[4096,1024] fp32.
// blocks of 128; global blocks {0,24}; qb attends {0,qb,24} (or all if qb global).

#define SEQ 4096
#define DIM 1024
#define NHEADS 16
#define HDIM 64
#define BS 128
#define ESTRIDE 136   // gemm epilogue staging pad

using short8 = __attribute__((ext_vector_type(8))) short;   // 8 x bf16 bits
using floatx4 = __attribute__((ext_vector_type(4))) float;

__device__ __forceinline__ float bf2f(short s) {
  unsigned u = ((unsigned)(unsigned short)s) << 16;
  return __uint_as_float(u);
}

__device__ __forceinline__ unsigned pack_bf16(float a, float b) {
  __hip_bfloat16 ba = __float2bfloat16(a);
  __hip_bfloat16 bb = __float2bfloat16(b);
  return ((unsigned)*(unsigned short*)&bb << 16) | (unsigned)*(unsigned short*)&ba;
}

__device__ __forceinline__ void gld_lds16(const __hip_bfloat16* g, __hip_bfloat16* l) {
  // 16B per lane, dest = wave-uniform base + lane*16 [guide §5, m97/m104]
  __builtin_amdgcn_global_load_lds(
      (const __attribute__((address_space(1))) unsigned int*)g,
      (__attribute__((address_space(3))) unsigned int*)l, 16, 0, 0);
}

// ---------------------------------------------------------------------------
// merged fp32 -> bf16 downcast for x (4096 blks), w_qkv (3072), w_out (1024)
// ---------------------------------------------------------------------------
__global__ __launch_bounds__(256) void downcast3(
    const float* __restrict__ x, const float* __restrict__ wq,
    const float* __restrict__ wo, __hip_bfloat16* __restrict__ xd,
    __hip_bfloat16* __restrict__ wqd, __hip_bfloat16* __restrict__ wod) {
  int id = blockIdx.x;
  const float* src;
  __hip_bfloat16* dst;
  int base;
  if (id < 4096) { src = x; dst = xd; base = id; }
  else if (id < 7168) { src = wq; dst = wqd; base = id - 4096; }
  else { src = wo; dst = wod; base = id - 7168; }
  int i = (base * 256 + threadIdx.x) * 4;
  float4 v = *(const float4*)(src + i);
  __hip_bfloat16 b0 = __float2bfloat16(v.x);
  __hip_bfloat16 b1 = __float2bfloat16(v.y);
  __hip_bfloat16 b2 = __float2bfloat16(v.z);
  __hip_bfloat16 b3 = __float2bfloat16(v.w);
  ushort4 packed = {*(unsigned short*)&b0, *(unsigned short*)&b1,
                    *(unsigned short*)&b2, *(unsigned short*)&b3};
  *(ushort4*)(((unsigned short*)dst) + i) = packed;
}

// ---------------------------------------------------------------------------
// QKV GEMM (unchanged): m97 K-loop + LDS-staged coalesced epilogue with
// operand swap for Q/K (transposed D) vs V (direct D -> Vt).
// ---------------------------------------------------------------------------
__global__ __launch_bounds__(256) void gemm_qkv(const __hip_bfloat16* __restrict__ Amat,
                                                const __hip_bfloat16* __restrict__ Wmat,
                                                const float* __restrict__ Bias,
                                                __hip_bfloat16* __restrict__ qkv) {
  __shared__ __align__(16) char pool[128 * ESTRIDE * 2];  // 34816 B
  __hip_bfloat16* Asmem = (__hip_bfloat16*)pool;
  __hip_bfloat16* Bsmem = (__hip_bfloat16*)(pool + 8192);
  __hip_bfloat16* Ep = (__hip_bfloat16*)pool;

  const int Kd = DIM;
  const int t = threadIdx.x;
  const int w = t >> 6;
  const int lane = t & 63;
  const int fr = lane & 15;
  const int quad = lane >> 4;
  const int wm = w >> 1, wn = w & 1;

  int id = blockIdx.x;
  int xcd = id & 7, j = id >> 3;
  int m_idx = xcd + (j & 3) * 8;
  int n_idx = j >> 2;
  const int m0 = m_idx * 128;
  const int n0 = n_idx * 128;
  const int s = n0 >> 10;
  const int cc0 = n0 & 1023;
  const bool vmode = (s == 2);

  const __hip_bfloat16* APtr = vmode ? Amat + (size_t)m0 * Kd : Wmat + (size_t)n0 * Kd;
  const __hip_bfloat16* BPtr = vmode ? Wmat + (size_t)n0 * Kd : Amat + (size_t)m0 * Kd;

  floatx4 acc[4][4];
#pragma unroll
  for (int i = 0; i < 4; ++i)
#pragma unroll
    for (int jj = 0; jj < 4; ++jj) acc[i][jj] = (floatx4){0.f, 0.f, 0.f, 0.f};

  for (int kk = 0; kk < Kd / 32; ++kk) {
#pragma unroll
    for (int jj = 0; jj < 2; ++jj) {
      int c = jj * 256 + t;
      int ldso = (jj * 256 + w * 64) * 8;
      gld_lds16(APtr + (size_t)(c >> 2) * Kd + kk * 32 + (c & 3) * 8, &Asmem[ldso]);
      gld_lds16(BPtr + (size_t)(c >> 2) * Kd + kk * 32 + (c & 3) * 8, &Bsmem[ldso]);
    }
    __syncthreads();
    short8 af[4], bf_[4];
#pragma unroll
    for (int mt = 0; mt < 4; ++mt)
      af[mt] = *(const short8*)&Asmem[(wm * 64 + mt * 16 + fr) * 32 + quad * 8];
#pragma unroll
    for (int nt = 0; nt < 4; ++nt)
      bf_[nt] = *(const short8*)&Bsmem[(wn * 64 + nt * 16 + fr) * 32 + quad * 8];
#pragma unroll
    for (int mt = 0; mt < 4; ++mt)
#pragma unroll
      for (int nt = 0; nt < 4; ++nt)
        acc[mt][nt] = __builtin_amdgcn_mfma_f32_16x16x32_bf16(af[mt], bf_[nt],
                                                              acc[mt][nt], 0, 0, 0);
    __syncthreads();
  }

#pragma unroll
  for (int nt = 0; nt < 4; ++nt) {
    int dcol = wn * 64 + nt * 16 + fr;
#pragma unroll
    for (int mt = 0; mt < 4; ++mt) {
      int drow0 = wm * 64 + mt * 16 + quad * 4;
      ushort4 pk;
      unsigned short* pks = (unsigned short*)&pk;
#pragma unroll
      for (int i = 0; i < 4; ++i) {
        __hip_bfloat16 bb = __float2bfloat16(acc[mt][nt][i]);
        pks[i] = *(unsigned short*)&bb;
      }
      *(ushort4*)&Ep[dcol * ESTRIDE + drow0] = pk;
    }
  }
  __syncthreads();

  if (!vmode) {
    __hip_bfloat16* dst = qkv + (size_t)s * SEQ * DIM;
#pragma unroll
    for (int rr = 0; rr < 8; ++rr) {
      int m = rr * 16 + (t >> 4);
      int ch = (t & 15) * 8;
      short8 v8 = *(const short8*)&Ep[m * ESTRIDE + ch];
      float4 b0 = *(const float4*)&Bias[n0 + ch];
      float4 b1 = *(const float4*)&Bias[n0 + ch + 4];
      float bb[8] = {b0.x, b0.y, b0.z, b0.w, b1.x, b1.y, b1.z, b1.w};
      short8 o8;
#pragma unroll
      for (int k = 0; k < 8; ++k) {
        __hip_bfloat16 ob = __float2bfloat16(bf2f(v8[k]) + bb[k]);
        o8[k] = *(short*)&ob;
      }
      *(short8*)&dst[(size_t)(m0 + m) * DIM + cc0 + ch] = o8;
    }
  } else {
    __hip_bfloat16* vt = qkv + 2ull * SEQ * DIM;
#pragma unroll
    for (int rr = 0; rr < 8; ++rr) {
      int nrow = rr * 16 + (t >> 4);
      int ch = (t & 15) * 8;
      float bv = Bias[n0 + nrow];
      short8 v8 = *(const short8*)&Ep[nrow * ESTRIDE + ch];
      short8 o8;
#pragma unroll
      for (int k = 0; k < 8; ++k) {
        __hip_bfloat16 ob = __float2bfloat16(bf2f(v8[k]) + bv);
        o8[k] = *(short*)&ob;
      }
      *(short8*)&vt[(size_t)(cc0 + nrow) * SEQ + m0 + ch] = o8;
    }
  }
}

// ---------------------------------------------------------------------------
// out-proj GEMM: 128x64 tiles -> 512 wgs (2/CU) (unchanged).
// ---------------------------------------------------------------------------
__global__ __launch_bounds__(256) void gemm_out(const __hip_bfloat16* __restrict__ Amat,
                                                const __hip_bfloat16* __restrict__ Wmat,
                                                const float* __restrict__ Bias,
                                                float* __restrict__ out) {
  __shared__ __align__(16) __hip_bfloat16 Asmem[128 * 32];
  __shared__ __align__(16) __hip_bfloat16 Bsmem[64 * 32];
  const int Kd = DIM;
  const int t = threadIdx.x;
  const int w = t >> 6;
  const int lane = t & 63;
  const int fr = lane & 15;
  const int quad = lane >> 4;
  const int wm = w >> 1, wn = w & 1;
  int id = blockIdx.x;
  int xcd = id & 7, j = id >> 3;       // j in [0,64)
  int m_idx = xcd + (j & 3) * 8;       // 0..31
  int n_idx = j >> 2;                  // 0..15
  const int m0 = m_idx * 128;
  const int n0 = n_idx * 64;
  const __hip_bfloat16* Ablk = Amat + (size_t)m0 * Kd;
  const __hip_bfloat16* Bblk = Wmat + (size_t)n0 * Kd;
  floatx4 acc[4][2];
#pragma unroll
  for (int i = 0; i < 4; ++i)
#pragma unroll
    for (int jj = 0; jj < 2; ++jj) acc[i][jj] = (floatx4){0.f, 0.f, 0.f, 0.f};
  for (int kk = 0; kk < Kd / 32; ++kk) {
#pragma unroll
    for (int jj = 0; jj < 2; ++jj) {
      int c = jj * 256 + t;
      int ldso = (jj * 256 + w * 64) * 8;
      gld_lds16(Ablk + (size_t)(c >> 2) * Kd + kk * 32 + (c & 3) * 8, &Asmem[ldso]);
    }
    gld_lds16(Bblk + (size_t)(t >> 2) * Kd + kk * 32 + (t & 3) * 8, &Bsmem[t * 8]);
    __syncthreads();
    short8 af[4], bf_[2];
#pragma unroll
    for (int mt = 0; mt < 4; ++mt)
      af[mt] = *(const short8*)&Asmem[(wm * 64 + mt * 16 + fr) * 32 + quad * 8];
#pragma unroll
    for (int nt = 0; nt < 2; ++nt)
      bf_[nt] = *(const short8*)&Bsmem[(wn * 32 + nt * 16 + fr) * 32 + quad * 8];
#pragma unroll
    for (int mt = 0; mt < 4; ++mt)
#pragma unroll
      for (int nt = 0; nt < 2; ++nt)
        acc[mt][nt] = __builtin_amdgcn_mfma_f32_16x16x32_bf16(af[mt], bf_[nt],
                                                              acc[mt][nt], 0, 0, 0);
    __syncthreads();
  }
#pragma unroll
  for (int nt = 0; nt < 2; ++nt) {
    int n = n0 + wn * 32 + nt * 16 + fr;
    float bv = Bias[n];
#pragma unroll
    for (int mt = 0; mt < 4; ++mt) {
      int m = m0 + wm * 64 + mt * 16 + quad * 4;
#pragma unroll
      for (int i = 0; i < 4; ++i)
        out[(size_t)(m + i) * DIM + n] = acc[mt][nt][i] + bv;
    }
  }
}

// ---------------------------------------------------------------------------
// MFMA flash attention v3: each wave processes TWO 16-row groups (+0, +64)
// against each staged K/V tile.
//  * Grid 46x16 = 736 wgs <= 1024 capacity (4 wgs/CU @ ~112 VGPR) -> ONE
//    residency round (R9 had 1472 wgs -> 2 rounds, 2nd 44% full).
//  * K/V staging DMA + FETCH halve (tiles reused by 2 rowgroups).
//  * Dual K/V buffers (32KB), 2 barriers/iter; per rowgroup: QK (16 MFMA),
//    lane-local softmax, verified select-after-shfl repack, PV (16 MFMA).
//  * NO min-waves bound (R10's (256,8) caused catastrophic spills).
// ---------------------------------------------------------------------------
__global__ __launch_bounds__(256) void attn_mfma(
    const __hip_bfloat16* __restrict__ qkv,
    __hip_bfloat16* __restrict__ aout,
    float* __restrict__ po, float* __restrict__ pm, float* __restrict__ pl) {
  __shared__ __align__(16) __hip_bfloat16 Kbuf[16 * 512];    // 16KB, 16 frags
  __shared__ __align__(16) __hip_bfloat16 Vbuf[16 * 512];    // 16KB, 16 frags
  const int h = blockIdx.y;
  const int wgid = blockIdx.x;
  const int t = threadIdx.x;
  const int wv = t >> 6;
  const int lane = t & 63;
  const int fr = lane & 15;
  const int quad = lane >> 4;

  int qb, niter, slice = 0, pid = 0;
  bool direct;
  if (wgid < 30) {
    qb = (wgid < 23) ? wgid + 1 : wgid + 2;   // 1..23, 25..31
    niter = 3;
    direct = true;
  } else {
    int gi = wgid - 30;                 // 0..15
    slice = gi & 7;
    int qc = gi >> 3;                   // 0 or 1
    qb = qc * 24;                       // 0 or 24
    niter = 4;
    direct = false;
    pid = (h * 2 + qc) * 8 + slice;
  }
  const int q0 = qb * BS;

  const __hip_bfloat16* Q = qkv;
  const __hip_bfloat16* K = qkv + (size_t)SEQ * DIM;
  const __hip_bfloat16* Vt = qkv + 2ull * SEQ * DIM;  // [DIM][SEQ]

  // Q B-frags for both rowgroups (rows +0 / +64)
  short8 qaA0, qaA1, qaB0, qaB1;
  {
    const __hip_bfloat16* qp =
        Q + (size_t)(q0 + wv * 16 + fr) * DIM + h * HDIM + quad * 8;
    qaA0 = *(const short8*)(qp);
    qaA1 = *(const short8*)(qp + 32);
    qp += (size_t)64 * DIM;
    qaB0 = *(const short8*)(qp);
    qaB1 = *(const short8*)(qp + 32);
  }

  float mA = -INFINITY, lA = 0.f, mB = -INFINITY, lB = 0.f;
  floatx4 oA[4], oB[4];
#pragma unroll
  for (int i = 0; i < 4; ++i) {
    oA[i] = (floatx4){0.f, 0.f, 0.f, 0.f};
    oB[i] = (floatx4){0.f, 0.f, 0.f, 0.f};
  }

  for (int bi = 0; bi < niter; ++bi) {
    int kb = direct ? (bi == 0 ? 0 : (bi == 1 ? qb : 24)) : slice * 4 + bi;

    // ---- cooperative frag-major staging of K and V tiles ----
    const __hip_bfloat16* Kg = K + (size_t)(kb * BS) * DIM + h * HDIM;
    const __hip_bfloat16* Vg = Vt + (size_t)(h * HDIM) * SEQ + kb * BS;
    __syncthreads();  // all waves done reading previous tiles
#pragma unroll
    for (int rr = 0; rr < 4; ++rr) {
      int f = rr * 4 + wv;              // wave-uniform frag id
      int nt = f >> 1, ks = f & 1;      // K frag coords
      gld_lds16(Kg + (size_t)(nt * 16 + fr) * DIM + ks * 32 + quad * 8,
                &Kbuf[f * 512]);
      int nt2 = f >> 2, ks2 = f & 3;    // V frag coords
      gld_lds16(Vg + (size_t)(nt2 * 16 + fr) * SEQ + ks2 * 32 + quad * 8,
                &Vbuf[f * 512]);
    }
    __syncthreads();  // DMA drained

    // ================= rowgroup A then B =================
#pragma unroll
    for (int rg = 0; rg < 2; ++rg) {
      short8 q0f = rg ? qaB0 : qaA0;
      short8 q1f = rg ? qaB1 : qaA1;
      float mrow = rg ? mB : mA;
      float lsum = rg ? lB : lA;

      // ---- St = K.Q^T: lane holds St[key=nt*16+quad*4+i][row=fr] ----
      floatx4 s[8];
#pragma unroll
      for (int nt = 0; nt < 8; ++nt) {
        short8 kf0 = *(const short8*)&Kbuf[(nt * 2 + 0) * 512 + lane * 8];
        short8 kf1 = *(const short8*)&Kbuf[(nt * 2 + 1) * 512 + lane * 8];
        floatx4 acc = {0.f, 0.f, 0.f, 0.f};
        acc = __builtin_amdgcn_mfma_f32_16x16x32_bf16(kf0, q0f, acc, 0, 0, 0);
        acc = __builtin_amdgcn_mfma_f32_16x16x32_bf16(kf1, q1f, acc, 0, 0, 0);
        s[nt] = acc;
      }
#pragma unroll
      for (int nt = 0; nt < 8; ++nt)
#pragma unroll
        for (int i = 0; i < 4; ++i) s[nt][i] *= 0.125f;

      // ---- lane-local online softmax (row = fr) ----
      float rmax = -INFINITY;
#pragma unroll
      for (int nt = 0; nt < 8; ++nt)
#pragma unroll
        for (int i = 0; i < 4; ++i) rmax = fmaxf(rmax, s[nt][i]);
      rmax = fmaxf(rmax, __shfl_xor(rmax, 16, 64));
      rmax = fmaxf(rmax, __shfl_xor(rmax, 32, 64));
      float newm = fmaxf(mrow, rmax);
      float alpha = __expf(mrow - newm);   // first iter: exp(-inf)=0
      float psum = 0.f;
      unsigned pki[8][2];
#pragma unroll
      for (int nt = 0; nt < 8; ++nt) {
        float p0 = __expf(s[nt][0] - newm);
        float p1 = __expf(s[nt][1] - newm);
        float p2 = __expf(s[nt][2] - newm);
        float p3 = __expf(s[nt][3] - newm);
        psum += (p0 + p1) + (p2 + p3);
        pki[nt][0] = pack_bf16(p0, p1);
        pki[nt][1] = pack_bf16(p2, p3);
      }
      psum += __shfl_xor(psum, 16, 64);
      psum += __shfl_xor(psum, 32, 64);
      lsum = lsum * alpha + psum;
      mrow = newm;
      if (rg) { mB = mrow; lB = lsum; } else { mA = mrow; lA = lsum; }

#pragma unroll
      for (int nt2 = 0; nt2 < 4; ++nt2)
#pragma unroll
        for (int i = 0; i < 4; ++i) {
          if (rg) oB[nt2][i] *= alpha; else oA[nt2][i] *= alpha;
        }

      // ---- repack + PV, ks2-outer (one pw live at a time) ----
#pragma unroll
      for (int ks2 = 0; ks2 < 4; ++ks2) {
        union { int w4[4]; short8 s8; } pw;
#pragma unroll
        for (int p = 0; p < 4; ++p) {
          int srcl = fr + ((((quad & 1) << 1) + (p >> 1)) << 4);
          int lo = __shfl((int)pki[2 * ks2][p & 1], srcl, 64);
          int hi = __shfl((int)pki[2 * ks2 + 1][p & 1], srcl, 64);
          pw.w4[p] = (quad & 2) ? hi : lo;
        }
#pragma unroll
        for (int nt2 = 0; nt2 < 4; ++nt2) {
          short8 vb = *(const short8*)&Vbuf[(nt2 * 4 + ks2) * 512 + lane * 8];
          if (rg)
            oB[nt2] = __builtin_amdgcn_mfma_f32_16x16x32_bf16(vb, pw.s8, oB[nt2], 0, 0, 0);
          else
            oA[nt2] = __builtin_amdgcn_mfma_f32_16x16x32_bf16(vb, pw.s8, oA[nt2], 0, 0, 0);
        }
      }
    }
  }

  // O^T C-layout: lane holds O[row=fr][d = nt2*16 + quad*4 + i] -> contiguous
  if (direct) {
#pragma unroll
    for (int rg = 0; rg < 2; ++rg) {
      float inv = 1.f / (rg ? lB : lA);
      __hip_bfloat16* orow = aout +
          (size_t)(q0 + rg * 64 + wv * 16 + fr) * DIM + h * HDIM + quad * 4;
#pragma unroll
      for (int nt2 = 0; nt2 < 4; ++nt2) {
        ushort4 pk;
        unsigned short* pks = (unsigned short*)&pk;
#pragma unroll
        for (int i = 0; i < 4; ++i) {
          float ov = rg ? oB[nt2][i] : oA[nt2][i];
          __hip_bfloat16 ob = __float2bfloat16(ov * inv);
          pks[i] = *(unsigned short*)&ob;
        }
        *(ushort4*)(orow + nt2 * 16) = pk;
      }
    }
  } else {
    // partials: po[pid][row 0..127][dim 0..63], pm/pl[pid][row]
#pragma unroll
    for (int rg = 0; rg < 2; ++rg) {
      float* pob = po + (size_t)pid * 8192 + (rg * 64 + wv * 16 + fr) * 64 + quad * 4;
#pragma unroll
      for (int nt2 = 0; nt2 < 4; ++nt2) {
        floatx4 ov = rg ? oB[nt2] : oA[nt2];
        float4 v = {ov[0], ov[1], ov[2], ov[3]};
        *(float4*)(pob + nt2 * 16) = v;
      }
      if (quad == 0) {
        pm[pid * 128 + rg * 64 + wv * 16 + fr] = rg ? mB : mA;
        pl[pid * 128 + rg * 64 + wv * 16 + fr] = rg ? lB : lA;
      }
    }
  }
}

// ---------------------------------------------------------------------------
// Combine 8 KV-slice partials for the global q-blocks (128-row layout).
// Grid 64: b2 -> h=b2>>2, qc=(b2>>1)&1, half=b2&1; thread: row_l=t>>2, 16 dims.
// ---------------------------------------------------------------------------
__global__ __launch_bounds__(256) void combine(const float* __restrict__ po,
                                               const float* __restrict__ pm,
                                               const float* __restrict__ pl,
                                               __hip_bfloat16* __restrict__ aout) {
  int b2 = blockIdx.x;
  int h = b2 >> 2, qc = (b2 >> 1) & 1, half = b2 & 1;
  int bb = h * 2 + qc;                 // pid block base
  int t = threadIdx.x;
  int row = half * 64 + (t >> 2);      // 0..127
  int d0 = (t & 3) * 16;

  float m8[8];
  float newm = -INFINITY;
#pragma unroll
  for (int s = 0; s < 8; ++s) {
    m8[s] = pm[(bb * 8 + s) * 128 + row];
    newm = fmaxf(newm, m8[s]);
  }
  float wgt[8], lsum = 0.f;
#pragma unroll
  for (int s = 0; s < 8; ++s) {
    wgt[s] = __expf(m8[s] - newm);
    lsum += pl[(bb * 8 + s) * 128 + row] * wgt[s];
  }
  float acc[16];
#pragma unroll
  for (int jj = 0; jj < 16; ++jj) acc[jj] = 0.f;
#pragma unroll
  for (int s = 0; s < 8; ++s) {
    const float* src = po + ((size_t)(bb * 8 + s) * 8192) + row * 64 + d0;
#pragma unroll
    for (int j4 = 0; j4 < 4; ++j4) {
      float4 v = *(const float4*)(src + j4 * 4);
      acc[j4 * 4 + 0] += wgt[s] * v.x;
      acc[j4 * 4 + 1] += wgt[s] * v.y;
      acc[j4 * 4 + 2] += wgt[s] * v.z;
      acc[j4 * 4 + 3] += wgt[s] * v.w;
    }
  }
  float inv = 1.f / lsum;
  int qrow = qc * 3072 + row;          // qb = qc*24 -> q0 = qc*3072
#pragma unroll
  for (int jj = 0; jj < 16; ++jj)
    aout[(size_t)qrow * DIM + h * HDIM + d0 + jj] = __float2bfloat16(acc[jj] * inv);
}

// ---------------------------------------------------------------------------
extern "C" void kernel_launch(void* const* d_in, const int* in_sizes, int n_in,
                              void* d_out, int out_size, void* d_ws, size_t ws_size,
                              hipStream_t stream) {
  const float* x = (const float*)d_in[0];
  const float* w_qkv = (const float*)d_in[1];
  const float* b_qkv = (const float*)d_in[2];
  const float* w_out = (const float*)d_in[3];
  const float* b_out = (const float*)d_in[4];
  float* out = (float*)d_out;

  // ws layout (bytes):
  //   [0,   24M) bf16 qkv: Q[SEQ][DIM], K[SEQ][DIM], Vt[DIM][SEQ]
  //   [24M, 32M) bf16 x_bf   -- dead after gemm_qkv; reused as po (8MB fp32)
  //   [32M, 38M) bf16 wqkv_bf -- dead after gemm_qkv; first 256KB reused as pm/pl
  //   [38M, 40M) bf16 wout_bf
  //   [40M, 48M) bf16 attn_ws [SEQ][DIM]
  char* wsb = (char*)d_ws;
  __hip_bfloat16* qkv_ws = (__hip_bfloat16*)(wsb);
  __hip_bfloat16* x_bf = (__hip_bfloat16*)(wsb + 24ull * 1024 * 1024);
  __hip_bfloat16* wqkv_bf = (__hip_bfloat16*)(wsb + 32ull * 1024 * 1024);
  __hip_bfloat16* wout_bf = (__hip_bfloat16*)(wsb + 38ull * 1024 * 1024);
  __hip_bfloat16* attn_ws = (__hip_bfloat16*)(wsb + 40ull * 1024 * 1024);
  float* po = (float*)(wsb + 24ull * 1024 * 1024);           // 256*128*64*4 = 8MB
  float* pm = (float*)(wsb + 32ull * 1024 * 1024);           // 128KB
  float* pl = (float*)(wsb + 32ull * 1024 * 1024 + 131072);  // 128KB

  dim3 blk(256);
  downcast3<<<dim3(8192), blk, 0, stream>>>(x, w_qkv, w_out, x_bf, wqkv_bf, wout_bf);
  gemm_qkv<<<dim3(768), blk, 0, stream>>>(x_bf, wqkv_bf, b_qkv, qkv_ws);
  attn_mfma<<<dim3(46, NHEADS), blk, 0, stream>>>(qkv_ws, attn_ws, po, pm, pl);
  combine<<<dim3(64), blk, 0, stream>>>(po, pm, pl, attn_ws);
  gemm_out<<<dim3(512), blk, 0, stream>>>(attn_ws, wout_bf, b_out, out);
}